// Round 9
// baseline (209.348 us; speedup 1.0000x reference)
//
#include <hip/hip_runtime.h>
#include <math.h>

// DigitCaps dynamic routing. B=256, R=1152, C=10, O=16, I=8, 3 iters.
// 8 dispatches. R9 deltas vs R8 (work-focused; boundaries measured ~4-5us):
//  - part layout [b][ks][n]: k_reduce waves stream contiguous 256B/step
//    (was 80KB-strided, latency-bound ~6us -> ~3.5us).
//  - k_gtdot inner loop vectorized over b: Xs[72k][36b], Vs[160n][36b]
//    (b-contiguous, 36 keeps f4 16B-aligned); 14 f4 LDS reads per 180 FMA
//    (was 64 scalar b32 per 180). Xs reads broadcast across lanes.
//  - k_gemm: unchanged inner (already ~fp32-FMA-floor); new part addressing.

#define B_ 256
#define R_ 1152
#define N_ 160      // C*O
#define K_ 9216     // R*I
#define NS 128      // K splits of 72 (9 routes)
#define KB 72
#define KC 24       // K per LDS stage (3 routes)
#define ASP 129     // As row stride

// workspace layout (float offsets)
#define PART_SZ (B_*NS*N_)      // 5,242,880 floats (21 MB), layout [b][ks][n]
#define BIJ_SZ  (R_*10)
#define V_SZ    (B_*N_)

// ---------------------------------------------------------------------------
// part[b][ks][n] += X[128 b][72 k] * (softmax_r(bij) ⊙ W)[72 k][160 n]
// grid 256 = (ks 0..127) x (bt 0..1); thread tile 8b x 10n
__global__ __launch_bounds__(256) void k_gemm(const float* __restrict__ X,
                                              const float* __restrict__ W,
                                              float* __restrict__ bij,
                                              float* __restrict__ part,
                                              int it) {
    __shared__ float As[KC * ASP];   // [k][b] transposed
    __shared__ float Bs[KC * 192];   // [k][16 groups of 12]
    __shared__ float cs[90];
    __shared__ float red[40];
    __shared__ float dsm[10];
    const int tid = threadIdx.x;
    const int ks = blockIdx.x >> 1, bt = blockIdx.x & 1;
    const int b0 = bt * 128, k0 = ks * KB, r0 = ks * 9;

    if (it == 0) {
        if (tid < 90) cs[tid] = 1.0f / 1152.0f;
        if (bt == 0 && tid < 90) bij[r0 * 10 + tid] = 0.0f;  // init for gtdot
    } else {
        float dcol[10];
        #pragma unroll
        for (int c = 0; c < 10; ++c) dcol[c] = 0.0f;
        for (int r = tid; r < R_; r += 256) {
            #pragma unroll
            for (int c = 0; c < 10; ++c) dcol[c] += __expf(bij[r * 10 + c]);
        }
        const int lane = tid & 63, wv = tid >> 6;
        #pragma unroll
        for (int c = 0; c < 10; ++c) {
            float s = dcol[c];
            #pragma unroll
            for (int off = 32; off > 0; off >>= 1) s += __shfl_down(s, off);
            if (lane == 0) red[wv * 10 + c] = s;
        }
        __syncthreads();
        if (tid < 10)
            dsm[tid] = red[tid] + red[10 + tid] + red[20 + tid] + red[30 + tid];
        __syncthreads();
        if (tid < 90) {
            int rr = tid / 10, cc = tid - rr * 10;
            cs[tid] = __expf(bij[(r0 + rr) * 10 + cc]) / dsm[cc];
        }
    }

    float acc[8][10];
    #pragma unroll
    for (int i = 0; i < 8; ++i)
        #pragma unroll
        for (int j = 0; j < 10; ++j) acc[i][j] = 0.0f;

    const int rg = tid >> 4;   // 16 groups x 8 b-rows
    const int cg = tid & 15;   // 16 groups x 10 n-cols

    for (int st = 0; st < 3; ++st) {
        __syncthreads();
        const int kc = k0 + st * KC;
        #pragma unroll
        for (int j = 0; j < 3; ++j) {           // A: 768 float4, transposed
            int q = j * 256 + tid;
            int bb = q / 6, kf = q - bb * 6;
            float4 a = *(const float4*)(X + (size_t)(b0 + bb) * K_ + kc + kf * 4);
            As[(kf * 4 + 0) * ASP + bb] = a.x;
            As[(kf * 4 + 1) * ASP + bb] = a.y;
            As[(kf * 4 + 2) * ASP + bb] = a.z;
            As[(kf * 4 + 3) * ASP + bb] = a.w;
        }
        const float* Wsl = W + (size_t)(r0 + st * 3) * 1280;
        #pragma unroll
        for (int j = 0; j < 4; ++j) {           // B: 960 float4, c-scaled
            int q = j * 256 + tid;
            if (q < 960) {
                int rl = q / 320;
                int rem = q - rl * 320;
                int c = rem >> 5;
                int o = (rem & 31) >> 1;
                int i4 = rem & 1;
                float4 w = *(const float4*)(Wsl + (size_t)q * 4);
                float sc = cs[(st * 3 + rl) * 10 + c];
                int nn = c * 16 + o;
                int grp = nn / 10;
                int pos = grp * 12 + (nn - grp * 10);
                int kk = rl * 8 + i4 * 4;
                Bs[(kk + 0) * 192 + pos] = w.x * sc;
                Bs[(kk + 1) * 192 + pos] = w.y * sc;
                Bs[(kk + 2) * 192 + pos] = w.z * sc;
                Bs[(kk + 3) * 192 + pos] = w.w * sc;
            }
        }
        __syncthreads();
        #pragma unroll 6
        for (int kk = 0; kk < KC; ++kk) {
            float4 a0 = *(const float4*)(&As[kk * ASP + rg * 8]);
            float4 a1 = *(const float4*)(&As[kk * ASP + rg * 8 + 4]);
            float4 v0 = *(const float4*)(&Bs[kk * 192 + cg * 12]);
            float4 v1 = *(const float4*)(&Bs[kk * 192 + cg * 12 + 4]);
            float2 v2 = *(const float2*)(&Bs[kk * 192 + cg * 12 + 8]);
            float av[8] = {a0.x, a0.y, a0.z, a0.w, a1.x, a1.y, a1.z, a1.w};
            float bv[10] = {v0.x, v0.y, v0.z, v0.w, v1.x, v1.y, v1.z, v1.w,
                            v2.x, v2.y};
            #pragma unroll
            for (int i = 0; i < 8; ++i)
                #pragma unroll
                for (int j = 0; j < 10; ++j) acc[i][j] += av[i] * bv[j];
        }
    }
    // part[b][ks][n]: 160 contiguous per (b,ks)
    float* P = part + (size_t)(b0 + rg * 8) * (NS * N_) + ks * N_ + cg * 10;
    #pragma unroll
    for (int i = 0; i < 8; ++i) {
        float* Pr = P + (size_t)i * (NS * N_);
        #pragma unroll
        for (int j = 0; j < 5; ++j)
            *(float2*)(Pr + j * 2) = make_float2(acc[i][j * 2], acc[i][j * 2 + 1]);
    }
}

// ---------------------------------------------------------------------------
// block b reduces its contiguous 80KB slab part[b][*][*]; wave reads 256B/step
__global__ void k_reduce(const float* __restrict__ part, float* __restrict__ out) {
    const int n = threadIdx.x, b = blockIdx.x;
    if (n < 160) {
        const float* p = part + (size_t)b * (NS * N_) + n;
        float s = 0.0f;
        #pragma unroll 8
        for (int ks = 0; ks < NS; ++ks) s += p[ks * N_];
        out[b * N_ + n] = s * fabsf(s) / (1.0f + s * s);  // elementwise squash
    }
}

// ---------------------------------------------------------------------------
// per block (kt: 72 k-rows = 9 routes; bh: 128 b):
//   G_partial[72x160] = sum_b X^T V  (4 b-stages of 32, b-vectorized f4 inner)
//   -> LDS -> bij[r,c] += (1/B) sum_{o,i} W[r,c,o,i]*G[...]  (atomicAdd)
__global__ __launch_bounds__(256) void k_gtdot(const float* __restrict__ X,
                                               const float* __restrict__ W,
                                               const float* __restrict__ V,
                                               float* __restrict__ bij) {
    __shared__ float L[72 * 165];    // 47.5 KB union
    float* Xs = L;                   // [72 k][36 b]  (b-contig, f4-aligned)
    float* Vs = L + 2592;            // [160 n][36 b]
    float* LG = L;                   // [72][165]
    const int tid = threadIdx.x;
    const int kt = blockIdx.x >> 1, bh = blockIdx.x & 1;
    const int k0 = kt * 72, r0 = kt * 9, b0 = bh * 128;
    const int rg = tid >> 5;   // 8 groups x 9 k-rows
    const int cg = tid & 31;   // 32 groups x 5 n-cols
    float acc[9][5];
    #pragma unroll
    for (int i = 0; i < 9; ++i)
        #pragma unroll
        for (int j = 0; j < 5; ++j) acc[i][j] = 0.0f;

    for (int sb = 0; sb < 4; ++sb) {
        __syncthreads();
        const int bb0 = b0 + sb * 32;
        #pragma unroll
        for (int j = 0; j < 3; ++j) {           // X: 576 f4 -> Xs[k][b]
            int q = j * 256 + tid;
            if (q < 576) {
                int bb = q / 18, kf = q - bb * 18;
                float4 a = *(const float4*)(X + (size_t)(bb0 + bb) * K_ + k0 + kf * 4);
                Xs[(kf * 4 + 0) * 36 + bb] = a.x;
                Xs[(kf * 4 + 1) * 36 + bb] = a.y;
                Xs[(kf * 4 + 2) * 36 + bb] = a.z;
                Xs[(kf * 4 + 3) * 36 + bb] = a.w;
            }
        }
        #pragma unroll
        for (int j = 0; j < 5; ++j) {           // V: 1280 f4 -> Vs[n][b]
            int q = j * 256 + tid;
            int bb = q / 40, nf = q - bb * 40;
            float4 v = *(const float4*)(V + (size_t)(bb0 + bb) * N_ + nf * 4);
            Vs[(nf * 4 + 0) * 36 + bb] = v.x;
            Vs[(nf * 4 + 1) * 36 + bb] = v.y;
            Vs[(nf * 4 + 2) * 36 + bb] = v.z;
            Vs[(nf * 4 + 3) * 36 + bb] = v.w;
        }
        __syncthreads();
        #pragma unroll 4
        for (int bq = 0; bq < 8; ++bq) {        // 4 b's per step, f4 reads
            float4 xv[9], vv[5];
            #pragma unroll
            for (int i = 0; i < 9; ++i)
                xv[i] = *(const float4*)(&Xs[(rg * 9 + i) * 36 + bq * 4]);
            #pragma unroll
            for (int j = 0; j < 5; ++j)
                vv[j] = *(const float4*)(&Vs[(cg * 5 + j) * 36 + bq * 4]);
            #pragma unroll
            for (int i = 0; i < 9; ++i)
                #pragma unroll
                for (int j = 0; j < 5; ++j)
                    acc[i][j] += xv[i].x * vv[j].x + xv[i].y * vv[j].y +
                                 xv[i].z * vv[j].z + xv[i].w * vv[j].w;
        }
    }
    // G tile -> LDS (overwrites staging), stride 165 breaks pow2 banks
    __syncthreads();
    #pragma unroll
    for (int i = 0; i < 9; ++i)
        #pragma unroll
        for (int j = 0; j < 5; ++j)
            LG[(rg * 9 + i) * 165 + cg * 5 + j] = acc[i][j];
    __syncthreads();
    if (tid < 90) {
        int rl = tid / 10, c = tid - rl * 10;
        int r = r0 + rl;
        const float4* wp = (const float4*)(W + (size_t)r * 1280 + c * 128);
        float s = 0.0f;
        #pragma unroll
        for (int o = 0; o < 16; ++o) {
            float4 wa = wp[o * 2], wb = wp[o * 2 + 1];
            const float* g = &LG[(rl * 8) * 165 + c * 16 + o];
            s += wa.x * g[0]       + wa.y * g[165]     + wa.z * g[2 * 165] +
                 wa.w * g[3 * 165] + wb.x * g[4 * 165] + wb.y * g[5 * 165] +
                 wb.z * g[6 * 165] + wb.w * g[7 * 165];
        }
        atomicAdd(&bij[r * 10 + c], s * (1.0f / B_));
    }
}

// ---------------------------------------------------------------------------
extern "C" void kernel_launch(void* const* d_in, const int* in_sizes, int n_in,
                              void* d_out, int out_size, void* d_ws, size_t ws_size,
                              hipStream_t stream) {
    const float* x = (const float*)d_in[0];   // (256, 1152, 8)
    const float* W = (const float*)d_in[1];   // (1152, 10, 16, 8)
    float* ws   = (float*)d_ws;
    float* part = ws;
    float* bij  = ws + PART_SZ;
    float* vws  = bij + BIJ_SZ;
    float* outf = (float*)d_out;

    for (int it = 0; it < 3; ++it) {
        k_gemm<<<256, 256, 0, stream>>>(x, W, bij, part, it);
        k_reduce<<<256, 256, 0, stream>>>(part, (it == 2) ? outf : vws);
        if (it < 2) k_gtdot<<<256, 256, 0, stream>>>(x, W, vws, bij);
    }
}

// Round 11
// 169.246 us; speedup vs baseline: 1.2369x; 1.2369x over previous
//
#include <hip/hip_runtime.h>
#include <math.h>

// DigitCaps dynamic routing. B=256, R=1152, C=10, O=16, I=8, 3 iters.
// 8 dispatches. R11 = R10 (bf16-MFMA k_gemm) with the k-pad zeroing bug
// fixed: MFMA reads k in [0,96); pad rows must be zeroed over 72..95
// (6 short4 chunks/row), R10 only zeroed 72..83 -> uninitialized LDS -> NaN.

#define B_ 256
#define R_ 1152
#define N_ 160      // C*O
#define K_ 9216     // R*I
#define NS 128      // K splits of 72 (9 routes)
#define KB 72
#define KP 96       // padded K per block (3 MFMA k-steps of 32)
#define LDK 104     // LDS k-stride (bf16 elems)

// workspace layout (float offsets)
#define PART_SZ (B_*NS*N_)      // 5,242,880 floats (21 MB), layout [b][ks][n]
#define BIJ_SZ  (R_*10)
#define V_SZ    (B_*N_)

typedef __attribute__((ext_vector_type(8))) short short8;
typedef __attribute__((ext_vector_type(4))) float f32x4;

static __device__ __forceinline__ short f2bf(float f) {   // RNE fp32->bf16
    unsigned u = __float_as_uint(f);
    unsigned r = (u + 0x7fffu + ((u >> 16) & 1u)) >> 16;
    return (short)r;
}

// ---------------------------------------------------------------------------
// part[b][ks][n] = X[128 b][72 k] * (softmax_r(bij) ⊙ W)[72 k][160 n]
// grid 256 = (ks 0..127) x (bt 0..1); bf16 MFMA 16x16x32;
// wave w: m-tiles {2w,2w+1} x 10 n-tiles; 3 k-steps; fp32 acc.
__global__ __launch_bounds__(256) void k_gemm(const float* __restrict__ X,
                                              const float* __restrict__ W,
                                              float* __restrict__ bij,
                                              float* __restrict__ part,
                                              int it) {
    __shared__ short As[128 * LDK];  // [m=b][k] bf16, 26.6 KB
    __shared__ short Bs[160 * LDK];  // [n][k] bf16 (B transposed), 33.3 KB
    __shared__ float cs[90];
    __shared__ float red[40];
    __shared__ float dsm[10];
    const int tid = threadIdx.x;
    const int ks = blockIdx.x >> 1, bt = blockIdx.x & 1;
    const int b0 = bt * 128, k0 = ks * KB, r0 = ks * 9;

    // ---- fused softmax over routes (axis 0), redundant per block ----
    if (it == 0) {
        if (tid < 90) cs[tid] = 1.0f / 1152.0f;
        if (bt == 0 && tid < 90) bij[r0 * 10 + tid] = 0.0f;  // init for gtdot
    } else {
        float dcol[10];
        #pragma unroll
        for (int c = 0; c < 10; ++c) dcol[c] = 0.0f;
        for (int r = tid; r < R_; r += 256) {
            #pragma unroll
            for (int c = 0; c < 10; ++c) dcol[c] += __expf(bij[r * 10 + c]);
        }
        const int lane = tid & 63, wv = tid >> 6;
        #pragma unroll
        for (int c = 0; c < 10; ++c) {
            float s = dcol[c];
            #pragma unroll
            for (int off = 32; off > 0; off >>= 1) s += __shfl_down(s, off);
            if (lane == 0) red[wv * 10 + c] = s;
        }
        __syncthreads();
        if (tid < 10)
            dsm[tid] = red[tid] + red[10 + tid] + red[20 + tid] + red[30 + tid];
        __syncthreads();
        if (tid < 90) {
            int rr = tid / 10, cc = tid - rr * 10;
            cs[tid] = __expf(bij[(r0 + rr) * 10 + cc]) / dsm[cc];
        }
    }

    // ---- stage A: X[128][72] -> bf16 As[m][k]; 2304 f4, 9/thread ----
    #pragma unroll
    for (int j = 0; j < 9; ++j) {
        int q = j * 256 + tid;
        int bb = q / 18, kf = q - bb * 18;
        float4 a = *(const float4*)(X + (size_t)(b0 + bb) * K_ + k0 + kf * 4);
        short4 h = make_short4(f2bf(a.x), f2bf(a.y), f2bf(a.z), f2bf(a.w));
        *(short4*)(&As[bb * LDK + kf * 4]) = h;
    }
    // zero A k-pad [72,96): 128 rows x 6 chunks of short4 = 768 (3 rounds)
    #pragma unroll
    for (int j = 0; j < 3; ++j) {
        int q = j * 256 + tid;
        int bb = q / 6, ch = q - bb * 6;
        *(short4*)(&As[bb * LDK + 72 + ch * 4]) = make_short4(0, 0, 0, 0);
    }
    // ---- stage B: (c ⊙ W)[72][160] -> bf16 Bs[n][k]; 2880 f4 ----
    {
        const float* Wsl = W + (size_t)r0 * 1280;
        #pragma unroll
        for (int j = 0; j < 12; ++j) {
            int q = j * 256 + tid;
            if (q < 2880) {
                int rl = q / 320;
                int rem = q - rl * 320;
                int c = rem >> 5;
                int o = (rem & 31) >> 1;
                int i4 = rem & 1;
                float4 w = *(const float4*)(Wsl + (size_t)q * 4);
                float sc = cs[rl * 10 + c];
                int nn = c * 16 + o;
                int kk = rl * 8 + i4 * 4;
                short4 h = make_short4(f2bf(w.x * sc), f2bf(w.y * sc),
                                       f2bf(w.z * sc), f2bf(w.w * sc));
                *(short4*)(&Bs[nn * LDK + kk]) = h;
            }
        }
        // zero B k-pad [72,96): 160 rows x 6 chunks = 960 (4 rounds)
        #pragma unroll
        for (int j = 0; j < 4; ++j) {
            int q = j * 256 + tid;
            if (q < 960) {
                int nn = q / 6, ch = q - nn * 6;
                *(short4*)(&Bs[nn * LDK + 72 + ch * 4]) = make_short4(0, 0, 0, 0);
            }
        }
    }
    __syncthreads();

    // ---- MFMA: wave w -> m-tiles {2w,2w+1} x n-tiles 0..9 ----
    const int wv = tid >> 6, lane = tid & 63;
    const int lrow = lane & 15, quad = lane >> 4;
    f32x4 acc[2][10];
    #pragma unroll
    for (int mi = 0; mi < 2; ++mi)
        #pragma unroll
        for (int nt = 0; nt < 10; ++nt) acc[mi][nt] = (f32x4)(0.0f);

    #pragma unroll
    for (int ksp = 0; ksp < 3; ++ksp) {
        const int ko = ksp * 32 + quad * 8;
        short8 afr[2], bfr[10];
        #pragma unroll
        for (int mi = 0; mi < 2; ++mi)
            afr[mi] = *(const short8*)(&As[((wv * 2 + mi) * 16 + lrow) * LDK + ko]);
        #pragma unroll
        for (int nt = 0; nt < 10; ++nt)
            bfr[nt] = *(const short8*)(&Bs[(nt * 16 + lrow) * LDK + ko]);
        #pragma unroll
        for (int mi = 0; mi < 2; ++mi)
            #pragma unroll
            for (int nt = 0; nt < 10; ++nt)
                acc[mi][nt] = __builtin_amdgcn_mfma_f32_16x16x32_bf16(
                    afr[mi], bfr[nt], acc[mi][nt], 0, 0, 0);
    }

    // ---- C store: row=(quad*4+reg), col=lrow; part[b][ks][n] ----
    #pragma unroll
    for (int mi = 0; mi < 2; ++mi) {
        int bbase = b0 + (wv * 2 + mi) * 16 + quad * 4;
        #pragma unroll
        for (int reg = 0; reg < 4; ++reg) {
            float* P = part + (size_t)(bbase + reg) * (NS * N_) + ks * N_ + lrow;
            #pragma unroll
            for (int nt = 0; nt < 10; ++nt)
                P[nt * 16] = acc[mi][nt][reg];
        }
    }
}

// ---------------------------------------------------------------------------
// block b reduces its contiguous 80KB slab part[b][*][*]; wave reads 256B/step
__global__ void k_reduce(const float* __restrict__ part, float* __restrict__ out) {
    const int n = threadIdx.x, b = blockIdx.x;
    if (n < 160) {
        const float* p = part + (size_t)b * (NS * N_) + n;
        float s = 0.0f;
        #pragma unroll 8
        for (int ks = 0; ks < NS; ++ks) s += p[ks * N_];
        out[b * N_ + n] = s * fabsf(s) / (1.0f + s * s);  // elementwise squash
    }
}

// ---------------------------------------------------------------------------
// per block (kt: 72 k-rows = 9 routes; bh: 128 b):
//   G_partial[72x160] = sum_b X^T V  (4 b-stages of 32, b-vectorized f4 inner)
//   -> LDS -> bij[r,c] += (1/B) sum_{o,i} W[r,c,o,i]*G[...]  (atomicAdd)
__global__ __launch_bounds__(256) void k_gtdot(const float* __restrict__ X,
                                               const float* __restrict__ W,
                                               const float* __restrict__ V,
                                               float* __restrict__ bij) {
    __shared__ float L[72 * 165];    // 47.5 KB union
    float* Xs = L;                   // [72 k][36 b]
    float* Vs = L + 2592;            // [160 n][36 b]
    float* LG = L;                   // [72][165]
    const int tid = threadIdx.x;
    const int kt = blockIdx.x >> 1, bh = blockIdx.x & 1;
    const int k0 = kt * 72, r0 = kt * 9, b0 = bh * 128;
    const int rg = tid >> 5;   // 8 groups x 9 k-rows
    const int cg = tid & 31;   // 32 groups x 5 n-cols
    float acc[9][5];
    #pragma unroll
    for (int i = 0; i < 9; ++i)
        #pragma unroll
        for (int j = 0; j < 5; ++j) acc[i][j] = 0.0f;

    for (int sb = 0; sb < 4; ++sb) {
        __syncthreads();
        const int bb0 = b0 + sb * 32;
        #pragma unroll
        for (int j = 0; j < 3; ++j) {           // X: 576 f4 -> Xs[k][b]
            int q = j * 256 + tid;
            if (q < 576) {
                int bb = q / 18, kf = q - bb * 18;
                float4 a = *(const float4*)(X + (size_t)(bb0 + bb) * K_ + k0 + kf * 4);
                Xs[(kf * 4 + 0) * 36 + bb] = a.x;
                Xs[(kf * 4 + 1) * 36 + bb] = a.y;
                Xs[(kf * 4 + 2) * 36 + bb] = a.z;
                Xs[(kf * 4 + 3) * 36 + bb] = a.w;
            }
        }
        #pragma unroll
        for (int j = 0; j < 5; ++j) {           // V: 1280 f4 -> Vs[n][b]
            int q = j * 256 + tid;
            int bb = q / 40, nf = q - bb * 40;
            float4 v = *(const float4*)(V + (size_t)(bb0 + bb) * N_ + nf * 4);
            Vs[(nf * 4 + 0) * 36 + bb] = v.x;
            Vs[(nf * 4 + 1) * 36 + bb] = v.y;
            Vs[(nf * 4 + 2) * 36 + bb] = v.z;
            Vs[(nf * 4 + 3) * 36 + bb] = v.w;
        }
        __syncthreads();
        #pragma unroll 4
        for (int bq = 0; bq < 8; ++bq) {        // 4 b's per step, f4 reads
            float4 xv[9], vv[5];
            #pragma unroll
            for (int i = 0; i < 9; ++i)
                xv[i] = *(const float4*)(&Xs[(rg * 9 + i) * 36 + bq * 4]);
            #pragma unroll
            for (int j = 0; j < 5; ++j)
                vv[j] = *(const float4*)(&Vs[(cg * 5 + j) * 36 + bq * 4]);
            #pragma unroll
            for (int i = 0; i < 9; ++i)
                #pragma unroll
                for (int j = 0; j < 5; ++j)
                    acc[i][j] += xv[i].x * vv[j].x + xv[i].y * vv[j].y +
                                 xv[i].z * vv[j].z + xv[i].w * vv[j].w;
        }
    }
    __syncthreads();
    #pragma unroll
    for (int i = 0; i < 9; ++i)
        #pragma unroll
        for (int j = 0; j < 5; ++j)
            LG[(rg * 9 + i) * 165 + cg * 5 + j] = acc[i][j];
    __syncthreads();
    if (tid < 90) {
        int rl = tid / 10, c = tid - rl * 10;
        int r = r0 + rl;
        const float4* wp = (const float4*)(W + (size_t)r * 1280 + c * 128);
        float s = 0.0f;
        #pragma unroll
        for (int o = 0; o < 16; ++o) {
            float4 wa = wp[o * 2], wb = wp[o * 2 + 1];
            const float* g = &LG[(rl * 8) * 165 + c * 16 + o];
            s += wa.x * g[0]       + wa.y * g[165]     + wa.z * g[2 * 165] +
                 wa.w * g[3 * 165] + wb.x * g[4 * 165] + wb.y * g[5 * 165] +
                 wb.z * g[6 * 165] + wb.w * g[7 * 165];
        }
        atomicAdd(&bij[r * 10 + c], s * (1.0f / B_));
    }
}

// ---------------------------------------------------------------------------
extern "C" void kernel_launch(void* const* d_in, const int* in_sizes, int n_in,
                              void* d_out, int out_size, void* d_ws, size_t ws_size,
                              hipStream_t stream) {
    const float* x = (const float*)d_in[0];   // (256, 1152, 8)
    const float* W = (const float*)d_in[1];   // (1152, 10, 16, 8)
    float* ws   = (float*)d_ws;
    float* part = ws;
    float* bij  = ws + PART_SZ;
    float* vws  = bij + BIJ_SZ;
    float* outf = (float*)d_out;

    for (int it = 0; it < 3; ++it) {
        k_gemm<<<256, 256, 0, stream>>>(x, W, bij, part, it);
        k_reduce<<<256, 256, 0, stream>>>(part, (it == 2) ? outf : vws);
        if (it < 2) k_gtdot<<<256, 256, 0, stream>>>(x, W, vws, bij);
    }
}

// Round 12
// 134.573 us; speedup vs baseline: 1.5556x; 1.2577x over previous
//
#include <hip/hip_runtime.h>
#include <math.h>

// DigitCaps dynamic routing. B=256, R=1152, C=10, O=16, I=8, 3 iters.
// 8 dispatches. R12 delta: k_gtdot moved to bf16 MFMA (16x16x32), matching
// R11's k_gemm win. G = X^T.V per block: M=72 k-rows (pad 80; garbage pad
// rows only affect discarded D rows), N=160, MFMA-K = b = 128 (4 k-steps).
// k_reduce now writes V transposed bf16 (Vt[n][256b], 80KB, L2-resident) so
// gtdot's B-staging is a vectorized short8 copy; X is scatter-transposed to
// bf16 at staging. k_gemm unchanged from R11.

#define B_ 256
#define R_ 1152
#define N_ 160      // C*O
#define K_ 9216     // R*I
#define NS 128      // K splits of 72 (9 routes)
#define KB 72
#define LDK 104     // gemm LDS k-stride (bf16 elems)
#define LDB 136     // gtdot LDS b-stride (bf16 elems; 272B rows, 16B aligned)

// workspace layout (float offsets)
#define PART_SZ (B_*NS*N_)      // 5,242,880 floats (21 MB), layout [b][ks][n]
#define BIJ_SZ  (R_*10)
#define VT_OFF  (PART_SZ+BIJ_SZ)   // Vt: 160*256 bf16 (80 KB)

typedef __attribute__((ext_vector_type(8))) short short8;
typedef __attribute__((ext_vector_type(4))) float f32x4;

static __device__ __forceinline__ short f2bf(float f) {   // RNE fp32->bf16
    unsigned u = __float_as_uint(f);
    unsigned r = (u + 0x7fffu + ((u >> 16) & 1u)) >> 16;
    return (short)r;
}

// ---------------------------------------------------------------------------
// part[b][ks][n] = X[128 b][72 k] * (softmax_r(bij) ⊙ W)[72 k][160 n]
// grid 256 = (ks 0..127) x (bt 0..1); bf16 MFMA 16x16x32 (R11, unchanged)
__global__ __launch_bounds__(256) void k_gemm(const float* __restrict__ X,
                                              const float* __restrict__ W,
                                              float* __restrict__ bij,
                                              float* __restrict__ part,
                                              int it) {
    __shared__ short As[128 * LDK];  // [m=b][k] bf16
    __shared__ short Bs[160 * LDK];  // [n][k] bf16 (B transposed)
    __shared__ float cs[90];
    __shared__ float red[40];
    __shared__ float dsm[10];
    const int tid = threadIdx.x;
    const int ks = blockIdx.x >> 1, bt = blockIdx.x & 1;
    const int b0 = bt * 128, k0 = ks * KB, r0 = ks * 9;

    if (it == 0) {
        if (tid < 90) cs[tid] = 1.0f / 1152.0f;
        if (bt == 0 && tid < 90) bij[r0 * 10 + tid] = 0.0f;  // init for gtdot
    } else {
        float dcol[10];
        #pragma unroll
        for (int c = 0; c < 10; ++c) dcol[c] = 0.0f;
        for (int r = tid; r < R_; r += 256) {
            #pragma unroll
            for (int c = 0; c < 10; ++c) dcol[c] += __expf(bij[r * 10 + c]);
        }
        const int lane = tid & 63, wv = tid >> 6;
        #pragma unroll
        for (int c = 0; c < 10; ++c) {
            float s = dcol[c];
            #pragma unroll
            for (int off = 32; off > 0; off >>= 1) s += __shfl_down(s, off);
            if (lane == 0) red[wv * 10 + c] = s;
        }
        __syncthreads();
        if (tid < 10)
            dsm[tid] = red[tid] + red[10 + tid] + red[20 + tid] + red[30 + tid];
        __syncthreads();
        if (tid < 90) {
            int rr = tid / 10, cc = tid - rr * 10;
            cs[tid] = __expf(bij[(r0 + rr) * 10 + cc]) / dsm[cc];
        }
    }

    // stage A: X[128][72] -> bf16 As[m][k]
    #pragma unroll
    for (int j = 0; j < 9; ++j) {
        int q = j * 256 + tid;
        int bb = q / 18, kf = q - bb * 18;
        float4 a = *(const float4*)(X + (size_t)(b0 + bb) * K_ + k0 + kf * 4);
        short4 h = make_short4(f2bf(a.x), f2bf(a.y), f2bf(a.z), f2bf(a.w));
        *(short4*)(&As[bb * LDK + kf * 4]) = h;
    }
    // zero A k-pad [72,96): 128 rows x 6 chunks
    #pragma unroll
    for (int j = 0; j < 3; ++j) {
        int q = j * 256 + tid;
        int bb = q / 6, ch = q - bb * 6;
        *(short4*)(&As[bb * LDK + 72 + ch * 4]) = make_short4(0, 0, 0, 0);
    }
    // stage B: (c ⊙ W)[72][160] -> bf16 Bs[n][k]
    {
        const float* Wsl = W + (size_t)r0 * 1280;
        #pragma unroll
        for (int j = 0; j < 12; ++j) {
            int q = j * 256 + tid;
            if (q < 2880) {
                int rl = q / 320;
                int rem = q - rl * 320;
                int c = rem >> 5;
                int o = (rem & 31) >> 1;
                int i4 = rem & 1;
                float4 w = *(const float4*)(Wsl + (size_t)q * 4);
                float sc = cs[rl * 10 + c];
                int nn = c * 16 + o;
                int kk = rl * 8 + i4 * 4;
                short4 h = make_short4(f2bf(w.x * sc), f2bf(w.y * sc),
                                       f2bf(w.z * sc), f2bf(w.w * sc));
                *(short4*)(&Bs[nn * LDK + kk]) = h;
            }
        }
        #pragma unroll
        for (int j = 0; j < 4; ++j) {
            int q = j * 256 + tid;
            if (q < 960) {
                int nn = q / 6, ch = q - nn * 6;
                *(short4*)(&Bs[nn * LDK + 72 + ch * 4]) = make_short4(0, 0, 0, 0);
            }
        }
    }
    __syncthreads();

    const int wv = tid >> 6, lane = tid & 63;
    const int lrow = lane & 15, quad = lane >> 4;
    f32x4 acc[2][10];
    #pragma unroll
    for (int mi = 0; mi < 2; ++mi)
        #pragma unroll
        for (int nt = 0; nt < 10; ++nt) acc[mi][nt] = (f32x4)(0.0f);

    #pragma unroll
    for (int ksp = 0; ksp < 3; ++ksp) {
        const int ko = ksp * 32 + quad * 8;
        short8 afr[2], bfr[10];
        #pragma unroll
        for (int mi = 0; mi < 2; ++mi)
            afr[mi] = *(const short8*)(&As[((wv * 2 + mi) * 16 + lrow) * LDK + ko]);
        #pragma unroll
        for (int nt = 0; nt < 10; ++nt)
            bfr[nt] = *(const short8*)(&Bs[(nt * 16 + lrow) * LDK + ko]);
        #pragma unroll
        for (int mi = 0; mi < 2; ++mi)
            #pragma unroll
            for (int nt = 0; nt < 10; ++nt)
                acc[mi][nt] = __builtin_amdgcn_mfma_f32_16x16x32_bf16(
                    afr[mi], bfr[nt], acc[mi][nt], 0, 0, 0);
    }

    #pragma unroll
    for (int mi = 0; mi < 2; ++mi) {
        int bbase = b0 + (wv * 2 + mi) * 16 + quad * 4;
        #pragma unroll
        for (int reg = 0; reg < 4; ++reg) {
            float* P = part + (size_t)(bbase + reg) * (NS * N_) + ks * N_ + lrow;
            #pragma unroll
            for (int nt = 0; nt < 10; ++nt)
                P[nt * 16] = acc[mi][nt][reg];
        }
    }
}

// ---------------------------------------------------------------------------
// block b: 128-way split-K sum + squash. Final iter -> fp32 out[b][n];
// else -> bf16 Vt[n][256b] (transposed, MFMA-ready for gtdot).
__global__ void k_reduce(const float* __restrict__ part, float* __restrict__ out,
                         short* __restrict__ vt, int fin) {
    const int n = threadIdx.x, b = blockIdx.x;
    if (n < 160) {
        const float* p = part + (size_t)b * (NS * N_) + n;
        float s = 0.0f;
        #pragma unroll 8
        for (int ks = 0; ks < NS; ++ks) s += p[ks * N_];
        float v = s * fabsf(s) / (1.0f + s * s);   // elementwise squash
        if (fin) out[b * N_ + n] = v;
        else     vt[n * 256 + b] = f2bf(v);
    }
}

// ---------------------------------------------------------------------------
// per block (kt: 72 k-rows = 9 routes; bh: 128 b), bf16 MFMA:
//   G[72x160] = X^T.V-half (M=72 pad 80, N=160, K=b=128, 4 k-steps)
//   -> LDS -> bij[r,c] += (1/B) sum_{o,i} W[r,c,o,i]*G[...]  (atomicAdd)
__global__ __launch_bounds__(256) void k_gtdot(const float* __restrict__ X,
                                               const float* __restrict__ W,
                                               const short* __restrict__ Vt,
                                               float* __restrict__ bij) {
    __shared__ short SM2[32640];     // As 80*136 + Bs 160*136 = 65.3 KB
    short* As = SM2;                 // [80 m=k-row][136 b]
    short* Bs = SM2 + 80 * LDB;      // [160 n][136 b]
    float* LG = (float*)SM2;         // [72][165] (union, after sync)
    const int tid = threadIdx.x;
    const int kt = blockIdx.x >> 1, bh = blockIdx.x & 1;
    const int k0 = kt * 72, r0 = kt * 9, b0 = bh * 128;

    // stage X -> As bf16 transposed ([k-row][b]); rows 72..79 left garbage
    // (A-row garbage only affects D rows 72..79, which are discarded)
    #pragma unroll
    for (int j = 0; j < 9; ++j) {
        int q = j * 256 + tid;                 // < 2304
        int bb = q / 18, kf = q - bb * 18;
        float4 a = *(const float4*)(X + (size_t)(b0 + bb) * K_ + k0 + kf * 4);
        As[(kf * 4 + 0) * LDB + bb] = f2bf(a.x);
        As[(kf * 4 + 1) * LDB + bb] = f2bf(a.y);
        As[(kf * 4 + 2) * LDB + bb] = f2bf(a.z);
        As[(kf * 4 + 3) * LDB + bb] = f2bf(a.w);
    }
    // stage Vt -> Bs (vector copy, already [n][b] bf16)
    #pragma unroll
    for (int j = 0; j < 10; ++j) {
        int q = j * 256 + tid;                 // < 2560
        int n = q >> 4, s = q & 15;
        *(short8*)(&Bs[n * LDB + s * 8]) =
            *(const short8*)(Vt + n * 256 + b0 + s * 8);
    }
    __syncthreads();

    // MFMA: wave wv handles n-tiles {wv, wv+4, wv+8(<10)} x m-tiles 0..4
    const int wv = tid >> 6, lane = tid & 63;
    const int lrow = lane & 15, quad = lane >> 4;
    f32x4 acc[5][3];
    #pragma unroll
    for (int mt = 0; mt < 5; ++mt)
        #pragma unroll
        for (int sl = 0; sl < 3; ++sl) acc[mt][sl] = (f32x4)(0.0f);

    #pragma unroll
    for (int kb = 0; kb < 4; ++kb) {
        const int ko = kb * 32 + quad * 8;
        short8 af[5], bf[3];
        #pragma unroll
        for (int mt = 0; mt < 5; ++mt)
            af[mt] = *(const short8*)(&As[(mt * 16 + lrow) * LDB + ko]);
        #pragma unroll
        for (int sl = 0; sl < 3; ++sl) {
            int nt = wv + sl * 4;
            if (nt < 10)
                bf[sl] = *(const short8*)(&Bs[(nt * 16 + lrow) * LDB + ko]);
        }
        #pragma unroll
        for (int mt = 0; mt < 5; ++mt)
            #pragma unroll
            for (int sl = 0; sl < 3; ++sl)
                if (wv + sl * 4 < 10)
                    acc[mt][sl] = __builtin_amdgcn_mfma_f32_16x16x32_bf16(
                        af[mt], bf[sl], acc[mt][sl], 0, 0, 0);
    }
    __syncthreads();   // all frag reads done; reuse LDS as LG

    #pragma unroll
    for (int mt = 0; mt < 5; ++mt) {
        #pragma unroll
        for (int sl = 0; sl < 3; ++sl) {
            int nt = wv + sl * 4;
            if (nt < 10) {
                #pragma unroll
                for (int reg = 0; reg < 4; ++reg) {
                    int m = mt * 16 + quad * 4 + reg;
                    if (m < 72)
                        LG[m * 165 + nt * 16 + lrow] = acc[mt][sl][reg];
                }
            }
        }
    }
    __syncthreads();
    // per-route dot with W (fp32), atomicAdd into bij
    if (tid < 90) {
        int rl = tid / 10, c = tid - rl * 10;
        int r = r0 + rl;
        const float4* wp = (const float4*)(W + (size_t)r * 1280 + c * 128);
        float s = 0.0f;
        #pragma unroll
        for (int o = 0; o < 16; ++o) {
            float4 wa = wp[o * 2], wb = wp[o * 2 + 1];
            const float* g = &LG[(rl * 8) * 165 + c * 16 + o];
            s += wa.x * g[0]       + wa.y * g[165]     + wa.z * g[2 * 165] +
                 wa.w * g[3 * 165] + wb.x * g[4 * 165] + wb.y * g[5 * 165] +
                 wb.z * g[6 * 165] + wb.w * g[7 * 165];
        }
        atomicAdd(&bij[r * 10 + c], s * (1.0f / B_));
    }
}

// ---------------------------------------------------------------------------
extern "C" void kernel_launch(void* const* d_in, const int* in_sizes, int n_in,
                              void* d_out, int out_size, void* d_ws, size_t ws_size,
                              hipStream_t stream) {
    const float* x = (const float*)d_in[0];   // (256, 1152, 8)
    const float* W = (const float*)d_in[1];   // (1152, 10, 16, 8)
    float* ws   = (float*)d_ws;
    float* part = ws;
    float* bij  = ws + PART_SZ;
    short* vt   = (short*)(ws + VT_OFF);      // Vt[160][256] bf16
    float* outf = (float*)d_out;

    for (int it = 0; it < 3; ++it) {
        k_gemm<<<256, 256, 0, stream>>>(x, W, bij, part, it);
        k_reduce<<<256, 256, 0, stream>>>(part, outf, vt, it == 2);
        if (it < 2) k_gtdot<<<256, 256, 0, stream>>>(x, W, vt, bij);
    }
}

// Round 13
// 130.926 us; speedup vs baseline: 1.5990x; 1.0279x over previous
//
#include <hip/hip_runtime.h>
#include <math.h>

// DigitCaps dynamic routing. B=256, R=1152, C=10, O=16, I=8, 3 iters.
// 8 dispatches. R13 delta: split-K partials stored fp16 (_Float16) — part
// HBM round-trip was the largest remaining work term (21MB w + 21MB r per
// iter, ~20us total). fp16 rel err 5e-4 on partials (~7e-3 magnitude) adds
// ~4e-5 to s — invisible vs the 4.9e-4 bf16-staging error. Structure
// unchanged: gemm(bf16 MFMA, fused softmax) -> reduce+squash -> gtdot
// (bf16 MFMA G=X^T.V -> W-dot -> atomicAdd bij).

#define B_ 256
#define R_ 1152
#define N_ 160      // C*O
#define K_ 9216     // R*I
#define NS 128      // K splits of 72 (9 routes)
#define KB 72
#define LDK 104     // gemm LDS k-stride (bf16 elems)
#define LDB 136     // gtdot LDS b-stride (bf16 elems)

// workspace layout (byte offsets)
#define PART_ELEMS ((size_t)B_*NS*N_)          // 5,242,880 fp16 = 10.49 MB
#define BIJ_BOFF   (PART_ELEMS*2)
#define VT_BOFF    (BIJ_BOFF + (size_t)R_*10*4)

typedef __attribute__((ext_vector_type(8))) short short8;
typedef __attribute__((ext_vector_type(4))) float f32x4;

static __device__ __forceinline__ short f2bf(float f) {   // RNE fp32->bf16
    unsigned u = __float_as_uint(f);
    unsigned r = (u + 0x7fffu + ((u >> 16) & 1u)) >> 16;
    return (short)r;
}

// ---------------------------------------------------------------------------
// part[b][ks][n] = X[128 b][72 k] * (softmax_r(bij) ⊙ W)[72 k][160 n]
// grid 256 = (ks 0..127) x (bt 0..1); bf16 MFMA 16x16x32; fp16 part out
__global__ __launch_bounds__(256) void k_gemm(const float* __restrict__ X,
                                              const float* __restrict__ W,
                                              float* __restrict__ bij,
                                              _Float16* __restrict__ part,
                                              int it) {
    __shared__ short As[128 * LDK];  // [m=b][k] bf16
    __shared__ short Bs[160 * LDK];  // [n][k] bf16 (B transposed)
    __shared__ float cs[90];
    __shared__ float red[40];
    __shared__ float dsm[10];
    const int tid = threadIdx.x;
    const int ks = blockIdx.x >> 1, bt = blockIdx.x & 1;
    const int b0 = bt * 128, k0 = ks * KB, r0 = ks * 9;

    if (it == 0) {
        if (tid < 90) cs[tid] = 1.0f / 1152.0f;
        if (bt == 0 && tid < 90) bij[r0 * 10 + tid] = 0.0f;  // init for gtdot
    } else {
        float dcol[10];
        #pragma unroll
        for (int c = 0; c < 10; ++c) dcol[c] = 0.0f;
        for (int r = tid; r < R_; r += 256) {
            #pragma unroll
            for (int c = 0; c < 10; ++c) dcol[c] += __expf(bij[r * 10 + c]);
        }
        const int lane = tid & 63, wv = tid >> 6;
        #pragma unroll
        for (int c = 0; c < 10; ++c) {
            float s = dcol[c];
            #pragma unroll
            for (int off = 32; off > 0; off >>= 1) s += __shfl_down(s, off);
            if (lane == 0) red[wv * 10 + c] = s;
        }
        __syncthreads();
        if (tid < 10)
            dsm[tid] = red[tid] + red[10 + tid] + red[20 + tid] + red[30 + tid];
        __syncthreads();
        if (tid < 90) {
            int rr = tid / 10, cc = tid - rr * 10;
            cs[tid] = __expf(bij[(r0 + rr) * 10 + cc]) / dsm[cc];
        }
    }

    // stage A: X[128][72] -> bf16 As[m][k]
    #pragma unroll
    for (int j = 0; j < 9; ++j) {
        int q = j * 256 + tid;
        int bb = q / 18, kf = q - bb * 18;
        float4 a = *(const float4*)(X + (size_t)(b0 + bb) * K_ + k0 + kf * 4);
        short4 h = make_short4(f2bf(a.x), f2bf(a.y), f2bf(a.z), f2bf(a.w));
        *(short4*)(&As[bb * LDK + kf * 4]) = h;
    }
    // zero A k-pad [72,96): 128 rows x 6 chunks
    #pragma unroll
    for (int j = 0; j < 3; ++j) {
        int q = j * 256 + tid;
        int bb = q / 6, ch = q - bb * 6;
        *(short4*)(&As[bb * LDK + 72 + ch * 4]) = make_short4(0, 0, 0, 0);
    }
    // stage B: (c ⊙ W)[72][160] -> bf16 Bs[n][k]
    {
        const float* Wsl = W + (size_t)r0 * 1280;
        #pragma unroll
        for (int j = 0; j < 12; ++j) {
            int q = j * 256 + tid;
            if (q < 2880) {
                int rl = q / 320;
                int rem = q - rl * 320;
                int c = rem >> 5;
                int o = (rem & 31) >> 1;
                int i4 = rem & 1;
                float4 w = *(const float4*)(Wsl + (size_t)q * 4);
                float sc = cs[rl * 10 + c];
                int nn = c * 16 + o;
                int kk = rl * 8 + i4 * 4;
                short4 h = make_short4(f2bf(w.x * sc), f2bf(w.y * sc),
                                       f2bf(w.z * sc), f2bf(w.w * sc));
                *(short4*)(&Bs[nn * LDK + kk]) = h;
            }
        }
        #pragma unroll
        for (int j = 0; j < 4; ++j) {
            int q = j * 256 + tid;
            if (q < 960) {
                int nn = q / 6, ch = q - nn * 6;
                *(short4*)(&Bs[nn * LDK + 72 + ch * 4]) = make_short4(0, 0, 0, 0);
            }
        }
    }
    __syncthreads();

    const int wv = tid >> 6, lane = tid & 63;
    const int lrow = lane & 15, quad = lane >> 4;
    f32x4 acc[2][10];
    #pragma unroll
    for (int mi = 0; mi < 2; ++mi)
        #pragma unroll
        for (int nt = 0; nt < 10; ++nt) acc[mi][nt] = (f32x4)(0.0f);

    #pragma unroll
    for (int ksp = 0; ksp < 3; ++ksp) {
        const int ko = ksp * 32 + quad * 8;
        short8 afr[2], bfr[10];
        #pragma unroll
        for (int mi = 0; mi < 2; ++mi)
            afr[mi] = *(const short8*)(&As[((wv * 2 + mi) * 16 + lrow) * LDK + ko]);
        #pragma unroll
        for (int nt = 0; nt < 10; ++nt)
            bfr[nt] = *(const short8*)(&Bs[(nt * 16 + lrow) * LDK + ko]);
        #pragma unroll
        for (int mi = 0; mi < 2; ++mi)
            #pragma unroll
            for (int nt = 0; nt < 10; ++nt)
                acc[mi][nt] = __builtin_amdgcn_mfma_f32_16x16x32_bf16(
                    afr[mi], bfr[nt], acc[mi][nt], 0, 0, 0);
    }

    // C store (fp16): row=(quad*4+reg), col=lrow; part[b][ks][n]
    #pragma unroll
    for (int mi = 0; mi < 2; ++mi) {
        int bbase = b0 + (wv * 2 + mi) * 16 + quad * 4;
        #pragma unroll
        for (int reg = 0; reg < 4; ++reg) {
            _Float16* P = part + (size_t)(bbase + reg) * (NS * N_) + ks * N_ + lrow;
            #pragma unroll
            for (int nt = 0; nt < 10; ++nt)
                P[nt * 16] = (_Float16)acc[mi][nt][reg];
        }
    }
}

// ---------------------------------------------------------------------------
// block b: 128-way split-K sum (fp16 part, fp32 acc) + squash.
// Final iter -> fp32 out[b][n]; else -> bf16 Vt[n][256b] (MFMA-ready).
__global__ void k_reduce(const _Float16* __restrict__ part,
                         float* __restrict__ out,
                         short* __restrict__ vt, int fin) {
    const int n = threadIdx.x, b = blockIdx.x;
    if (n < 160) {
        const _Float16* p = part + (size_t)b * (NS * N_) + n;
        float s = 0.0f;
        #pragma unroll 8
        for (int ks = 0; ks < NS; ++ks) s += (float)p[ks * N_];
        float v = s * fabsf(s) / (1.0f + s * s);   // elementwise squash
        if (fin) out[b * N_ + n] = v;
        else     vt[n * 256 + b] = f2bf(v);
    }
}

// ---------------------------------------------------------------------------
// per block (kt: 72 k-rows = 9 routes; bh: 128 b), bf16 MFMA:
//   G[72x160] = X^T.V-half (M=72 pad 80, N=160, K=b=128, 4 k-steps)
//   -> LDS -> bij[r,c] += (1/B) sum_{o,i} W[r,c,o,i]*G[...]  (atomicAdd)
__global__ __launch_bounds__(256) void k_gtdot(const float* __restrict__ X,
                                               const float* __restrict__ W,
                                               const short* __restrict__ Vt,
                                               float* __restrict__ bij) {
    __shared__ short SM2[32640];     // As 80*136 + Bs 160*136 = 65.3 KB
    short* As = SM2;                 // [80 m=k-row][136 b]
    short* Bs = SM2 + 80 * LDB;      // [160 n][136 b]
    float* LG = (float*)SM2;         // [72][165] (union, after sync)
    const int tid = threadIdx.x;
    const int kt = blockIdx.x >> 1, bh = blockIdx.x & 1;
    const int k0 = kt * 72, r0 = kt * 9, b0 = bh * 128;

    // stage X -> As bf16 transposed; pad rows 72..79 garbage (discarded D rows)
    #pragma unroll
    for (int j = 0; j < 9; ++j) {
        int q = j * 256 + tid;                 // < 2304
        int bb = q / 18, kf = q - bb * 18;
        float4 a = *(const float4*)(X + (size_t)(b0 + bb) * K_ + k0 + kf * 4);
        As[(kf * 4 + 0) * LDB + bb] = f2bf(a.x);
        As[(kf * 4 + 1) * LDB + bb] = f2bf(a.y);
        As[(kf * 4 + 2) * LDB + bb] = f2bf(a.z);
        As[(kf * 4 + 3) * LDB + bb] = f2bf(a.w);
    }
    // stage Vt -> Bs (vector copy, already [n][b] bf16)
    #pragma unroll
    for (int j = 0; j < 10; ++j) {
        int q = j * 256 + tid;                 // < 2560
        int n = q >> 4, s = q & 15;
        *(short8*)(&Bs[n * LDB + s * 8]) =
            *(const short8*)(Vt + n * 256 + b0 + s * 8);
    }
    __syncthreads();

    // MFMA: wave wv handles n-tiles {wv, wv+4, wv+8(<10)} x m-tiles 0..4
    const int wv = tid >> 6, lane = tid & 63;
    const int lrow = lane & 15, quad = lane >> 4;
    f32x4 acc[5][3];
    #pragma unroll
    for (int mt = 0; mt < 5; ++mt)
        #pragma unroll
        for (int sl = 0; sl < 3; ++sl) acc[mt][sl] = (f32x4)(0.0f);

    #pragma unroll
    for (int kb = 0; kb < 4; ++kb) {
        const int ko = kb * 32 + quad * 8;
        short8 af[5], bf[3];
        #pragma unroll
        for (int mt = 0; mt < 5; ++mt)
            af[mt] = *(const short8*)(&As[(mt * 16 + lrow) * LDB + ko]);
        #pragma unroll
        for (int sl = 0; sl < 3; ++sl) {
            int nt = wv + sl * 4;
            if (nt < 10)
                bf[sl] = *(const short8*)(&Bs[(nt * 16 + lrow) * LDB + ko]);
        }
        #pragma unroll
        for (int mt = 0; mt < 5; ++mt)
            #pragma unroll
            for (int sl = 0; sl < 3; ++sl)
                if (wv + sl * 4 < 10)
                    acc[mt][sl] = __builtin_amdgcn_mfma_f32_16x16x32_bf16(
                        af[mt], bf[sl], acc[mt][sl], 0, 0, 0);
    }
    __syncthreads();   // all frag reads done; reuse LDS as LG

    #pragma unroll
    for (int mt = 0; mt < 5; ++mt) {
        #pragma unroll
        for (int sl = 0; sl < 3; ++sl) {
            int nt = wv + sl * 4;
            if (nt < 10) {
                #pragma unroll
                for (int reg = 0; reg < 4; ++reg) {
                    int m = mt * 16 + quad * 4 + reg;
                    if (m < 72)
                        LG[m * 165 + nt * 16 + lrow] = acc[mt][sl][reg];
                }
            }
        }
    }
    __syncthreads();
    // per-route dot with W (fp32), atomicAdd into bij
    if (tid < 90) {
        int rl = tid / 10, c = tid - rl * 10;
        int r = r0 + rl;
        const float4* wp = (const float4*)(W + (size_t)r * 1280 + c * 128);
        float s = 0.0f;
        #pragma unroll
        for (int o = 0; o < 16; ++o) {
            float4 wa = wp[o * 2], wb = wp[o * 2 + 1];
            const float* g = &LG[(rl * 8) * 165 + c * 16 + o];
            s += wa.x * g[0]       + wa.y * g[165]     + wa.z * g[2 * 165] +
                 wa.w * g[3 * 165] + wb.x * g[4 * 165] + wb.y * g[5 * 165] +
                 wb.z * g[6 * 165] + wb.w * g[7 * 165];
        }
        atomicAdd(&bij[r * 10 + c], s * (1.0f / B_));
    }
}

// ---------------------------------------------------------------------------
extern "C" void kernel_launch(void* const* d_in, const int* in_sizes, int n_in,
                              void* d_out, int out_size, void* d_ws, size_t ws_size,
                              hipStream_t stream) {
    const float* x = (const float*)d_in[0];   // (256, 1152, 8)
    const float* W = (const float*)d_in[1];   // (1152, 10, 16, 8)
    char* ws      = (char*)d_ws;
    _Float16* part = (_Float16*)ws;
    float* bij    = (float*)(ws + BIJ_BOFF);
    short* vt     = (short*)(ws + VT_BOFF);   // Vt[160][256] bf16
    float* outf   = (float*)d_out;

    for (int it = 0; it < 3; ++it) {
        k_gemm<<<256, 256, 0, stream>>>(x, W, bij, part, it);
        k_reduce<<<256, 256, 0, stream>>>(part, outf, vt, it == 2);
        if (it < 2) k_gtdot<<<256, 256, 0, stream>>>(x, W, vt, bij);
    }
}